// Round 6
// baseline (854.740 us; speedup 1.0000x reference)
//
#include <hip/hip_runtime.h>
#include <cstddef>

typedef short bf16x8 __attribute__((ext_vector_type(8)));
typedef float f32x4 __attribute__((ext_vector_type(4)));

__device__ __forceinline__ float sigm(float x) { return 1.f / (1.f + expf(-x)); }

// f32 -> bf16 (round to nearest even)
__device__ __forceinline__ unsigned short f2bf(float f) {
    union { float f; unsigned u; } v; v.f = f;
    return (unsigned short)((v.u + 0x7FFFu + ((v.u >> 16) & 1u)) >> 16);
}
// unpack bf16 pair
__device__ __forceinline__ float bflo(unsigned u) {
    union { unsigned u; float f; } v; v.u = u << 16; return v.f;
}
__device__ __forceinline__ float bfhi(unsigned u) {
    union { unsigned u; float f; } v; v.u = u & 0xFFFF0000u; return v.f;
}

// ============================================================================
// prep_cast: one pass producing all bf16 operands.
// ============================================================================
#define N0 (20160 * 160)
#define N1 (2048 * 160)
#define N2 (2048 * 256)

__global__ __launch_bounds__(256) void prep_cast(
    const int* __restrict__ ids, const int* __restrict__ titles,
    const float* __restrict__ emb,
    const float* __restrict__ swf, const float* __restrict__ swb,
    const float* __restrict__ dwf, const float* __restrict__ dwb,
    unsigned* __restrict__ Abf, unsigned* __restrict__ Wsen,
    unsigned* __restrict__ Wdoc)
{
    int idx = blockIdx.x * 256 + threadIdx.x;
    if (idx < N0) {
        int row = idx / 160, kk = idx - row * 160;
        int id = (row < 19200) ? ids[row] : titles[row - 19200];
        float a = 0.f, b = 0.f;
        if (kk < 150) {
            const float* s = emb + (size_t)id * 300 + kk * 2;
            a = s[0]; b = s[1];
        }
        Abf[idx] = (unsigned)f2bf(a) | ((unsigned)f2bf(b) << 16);
    } else if (idx < N0 + N1) {
        int j = idx - N0;
        int row = j / 160, kk = j - row * 160;
        const float* base = (row < 1024) ? swf + (size_t)row * 300
                                         : swb + (size_t)(row - 1024) * 300;
        float a = 0.f, b = 0.f;
        if (kk < 150) { a = base[kk * 2]; b = base[kk * 2 + 1]; }
        Wsen[j] = (unsigned)f2bf(a) | ((unsigned)f2bf(b) << 16);
    } else if (idx < N0 + N1 + N2) {
        int j = idx - N0 - N1;
        int row = j >> 8, kk = j & 255;
        const float* base = (row < 1024) ? dwf + (size_t)row * 512
                                         : dwb + (size_t)(row - 1024) * 512;
        Wdoc[j] = (unsigned)f2bf(base[kk * 2]) | ((unsigned)f2bf(base[kk * 2 + 1]) << 16);
    }
}

// ============================================================================
// proj_mfma: out[M][2048] = Abf[M][Kp] @ Wbf^T + bias.  OUTPUT = packed bf16,
// gate-interleaved: elem = half*1024 + unit*4 + gate (i,f,g,o).
// ============================================================================
__global__ __launch_bounds__(256) void proj_mfma(
    const unsigned short* __restrict__ Abf, int M, int Kp,
    const unsigned short* __restrict__ Wbf,
    const float* __restrict__ bf_, const float* __restrict__ bb_,
    unsigned short* __restrict__ out)
{
    __shared__ unsigned short As[128 * 40];   // pitch 80B (16B aligned)
    __shared__ unsigned short Ws[128 * 40];
    const int tid  = threadIdx.x;
    const int lane = tid & 63;
    const int w    = tid >> 6;
    const int n    = lane & 15;
    const int quad = lane >> 4;
    const int bm   = blockIdx.x * 128;
    const int by   = blockIdx.y;              // 0..15
    const int half = by >> 3;
    const int ug32 = (by & 7) * 32;
    const unsigned short* Wb = Wbf + (size_t)half * 1024 * Kp;
    const float* biasp = half ? bb_ : bf_;

    f32x4 acc[2][8];
#pragma unroll
    for (int rt = 0; rt < 2; rt++)
#pragma unroll
        for (int ct = 0; ct < 8; ct++) acc[rt][ct] = (f32x4){0.f, 0.f, 0.f, 0.f};

    const int chunks = Kp >> 5;
    for (int kc = 0; kc < chunks; kc++) {
        const int k0 = kc * 32;
#pragma unroll
        for (int j = 0; j < 2; j++) {
            int idx = j * 256 + tid;
            int arow = idx >> 2, qq = idx & 3;
            int grow = bm + arow; if (grow >= M) grow = M - 1;
            *(uint4*)&As[arow * 40 + qq * 8] =
                *(const uint4*)(Abf + (size_t)grow * Kp + k0 + qq * 8);
            int cc = idx >> 2;
            int wrow = (cc >> 5) * 256 + ug32 + (cc & 31);   // gate=cc>>5
            *(uint4*)&Ws[cc * 40 + qq * 8] =
                *(const uint4*)(Wb + (size_t)wrow * Kp + k0 + qq * 8);
        }
        __syncthreads();
        bf16x8 Aq[2], Bq[8];
#pragma unroll
        for (int rt = 0; rt < 2; rt++)
            Aq[rt] = *(const bf16x8*)&As[((w * 2 + rt) * 16 + n) * 40 + quad * 8];
#pragma unroll
        for (int ct = 0; ct < 8; ct++)
            Bq[ct] = *(const bf16x8*)&Ws[(ct * 16 + n) * 40 + quad * 8];
#pragma unroll
        for (int rt = 0; rt < 2; rt++)
#pragma unroll
            for (int ct = 0; ct < 8; ct++)
                acc[rt][ct] = __builtin_amdgcn_mfma_f32_16x16x32_bf16(
                    Aq[rt], Bq[ct], acc[rt][ct], 0, 0, 0);
        __syncthreads();
    }

    // acc[rt][2g+s] = gate g, unit s*16+n
#pragma unroll
    for (int s = 0; s < 2; s++) {
        const int uL = s * 16 + n;
        float b0 = biasp[ug32 + uL];
        float b1 = biasp[256 + ug32 + uL];
        float b2 = biasp[512 + ug32 + uL];
        float b3 = biasp[768 + ug32 + uL];
#pragma unroll
        for (int rt = 0; rt < 2; rt++) {
#pragma unroll
            for (int r = 0; r < 4; r++) {
                int row = bm + (w * 2 + rt) * 16 + quad * 4 + r;
                if (row >= M) continue;
                float gi = acc[rt][0 + s][r] + b0;
                float gf = acc[rt][2 + s][r] + b1;
                float gg = acc[rt][4 + s][r] + b2;
                float go = acc[rt][6 + s][r] + b3;
                uint2 pk;
                pk.x = (unsigned)f2bf(gi) | ((unsigned)f2bf(gf) << 16);
                pk.y = (unsigned)f2bf(gg) | ((unsigned)f2bf(go) << 16);
                *(uint2*)(out + (size_t)row * 2048 + half * 1024 + (ug32 + uL) * 4) = pk;
            }
        }
    }
}

__device__ __forceinline__ const unsigned short* sen_xbase(
    const unsigned short* xw, const unsigned short* xw_head, int grow_e, int t)
{
    if (grow_e < 640)       return xw + ((size_t)grow_e * 30 + t) * 2048;
    else if (grow_e < 1280) return xw + ((size_t)(grow_e - 640) * 30 + 29 - t) * 2048 + 1024;
    else if (grow_e < 1344) return xw_head + ((size_t)(grow_e - 1280) * 15 + t) * 2048;
    else                    return xw_head + ((size_t)(grow_e - 1344) * 15 + 14 - t) * 2048 + 1024;
}

// ============================================================================
// lstm_sen: persistent BiLSTM, grid (16 unit-groups, 22 row-groups).
// Barrier: monotonic counter, all-relaxed agent atomics; arrive -> prefetch ->
// poll so the xw prefetch drain doesn't delay arrival.
// ============================================================================
__global__ __launch_bounds__(256, 2) void lstm_sen(
    const unsigned short* __restrict__ xw, const unsigned short* __restrict__ xw_head,
    const float* __restrict__ whh_f, const float* __restrict__ whh_b,
    unsigned short* hbA, unsigned short* hbB,
    float* __restrict__ sentences, float* __restrict__ headings,
    unsigned* bars)
{
    const int tid  = threadIdx.x;
    const int lane = tid & 63;
    const int w    = tid >> 6;
    const int n    = lane & 15;
    const int quad = lane >> 4;
    const int ug   = blockIdx.x;       // 0..15
    const int rg   = blockIdx.y;       // 0..21
    const int r0   = rg * 64;
    const int u0   = ug * 16;
    const bool bwd  = (rg >= 10 && rg < 20) || (rg == 21);
    const bool head = (rg >= 20);
    const float* whh = bwd ? whh_b : whh_f;
    unsigned* cnt = bars + rg * 16;    // 64B-separated counters
    const int tEnd = head ? 15 : 30;

    __shared__ float G[64][68];        // row pitch 272B (16B aligned)

    // Whh -> register B-frags (col cc=ct*16+n -> unit cc>>2, gate cc&3)
    bf16x8 Bf[4][8];
#pragma unroll
    for (int ct = 0; ct < 4; ct++) {
        const int c    = ct * 16 + n;
        const int grow = (c & 3) * 256 + u0 + (c >> 2);
        const float* wr = whh + (size_t)grow * 256;
#pragma unroll
        for (int ks = 0; ks < 8; ks++) {
            union { bf16x8 v; short s[8]; } tmp;
            const float* p = wr + ks * 32 + quad * 8;
#pragma unroll
            for (int j = 0; j < 8; j++) tmp.s[j] = (short)f2bf(p[j]);
            Bf[ct][ks] = tmp.v;
        }
    }

    float cr[4] = {0.f, 0.f, 0.f, 0.f};
    const int rr = tid >> 2;
    const int us = (tid & 3) * 4;             // local unit base
    const int grow_e = r0 + rr;

    // preload xw slice for t=0 (16 bf16 = 2 x uint4)
    uint4 xq0, xq1;
    {
        const uint4* xp = (const uint4*)(sen_xbase(xw, xw_head, grow_e, 0)
                                         + (size_t)(u0 + us) * 4);
        xq0 = xp[0]; xq1 = xp[1];
    }

    for (int t = 0; t < tEnd; t++) {
        const unsigned short* hp = (t & 1) ? hbB : hbA;
        unsigned short*       hq = (t & 1) ? hbA : hbB;

        // ---- hidden GEMM (MFMA) ----
        {
            const unsigned long long* hrow =
                (const unsigned long long*)(hp + (size_t)(r0 + w * 16 + n) * 256);
            unsigned long long a0[8], a1[8];
#pragma unroll
            for (int ks = 0; ks < 8; ks++) {
                a0[ks] = __hip_atomic_load(hrow + ks * 8 + quad * 2,
                                           __ATOMIC_RELAXED, __HIP_MEMORY_SCOPE_AGENT);
                a1[ks] = __hip_atomic_load(hrow + ks * 8 + quad * 2 + 1,
                                           __ATOMIC_RELAXED, __HIP_MEMORY_SCOPE_AGENT);
            }
            f32x4 acc[4];
#pragma unroll
            for (int ct = 0; ct < 4; ct++) acc[ct] = (f32x4){0.f, 0.f, 0.f, 0.f};
#pragma unroll
            for (int ks = 0; ks < 8; ks++) {
                union { bf16x8 v; unsigned long long q[2]; } af;
                af.q[0] = a0[ks]; af.q[1] = a1[ks];
#pragma unroll
                for (int ct = 0; ct < 4; ct++)
                    acc[ct] = __builtin_amdgcn_mfma_f32_16x16x32_bf16(
                        af.v, Bf[ct][ks], acc[ct], 0, 0, 0);
            }
#pragma unroll
            for (int ct = 0; ct < 4; ct++)
#pragma unroll
                for (int r = 0; r < 4; r++)
                    G[w * 16 + quad * 4 + r][ct * 16 + n] = acc[ct][r];
        }
        __syncthreads();

        // ---- gate epilogue ----
        {
            float* fdst = nullptr;
            if (!head) {
                if (t == 29) fdst = sentences +
                    (size_t)(bwd ? grow_e - 640 : grow_e) * 512 + (bwd ? 256 : 0);
            } else {
                if (t == 14) fdst = headings +
                    (size_t)(grow_e - (bwd ? 1344 : 1280)) * 512 + (bwd ? 256 : 0);
            }
            const unsigned xwv[8] = {xq0.x, xq0.y, xq0.z, xq0.w,
                                     xq1.x, xq1.y, xq1.z, xq1.w};
            const float4* Gp = (const float4*)&G[rr][us * 4];
            unsigned long long hpack = 0ull;
            float hout[4];
#pragma unroll
            for (int p = 0; p < 4; p++) {
                float4 gv = Gp[p];
                unsigned wif = xwv[2 * p], wgo = xwv[2 * p + 1];
                float gi = gv.x + bflo(wif);
                float gf = gv.y + bfhi(wif);
                float gg = gv.z + bflo(wgo);
                float go = gv.w + bfhi(wgo);
                float cn = sigm(gf) * cr[p] + sigm(gi) * tanhf(gg);
                float hn = sigm(go) * tanhf(cn);
                cr[p] = cn; hout[p] = hn;
                hpack |= ((unsigned long long)f2bf(hn)) << (16 * p);
            }
            __hip_atomic_store((unsigned long long*)(hq + (size_t)grow_e * 256 + u0 + us),
                               hpack, __ATOMIC_RELAXED, __HIP_MEMORY_SCOPE_AGENT);
            if (fdst) *(float4*)(fdst + u0 + us) = *(float4*)hout;
        }

        if (t + 1 < tEnd) {
            __syncthreads();   // drains h store; guards G reuse
            if (tid == 0)
                __hip_atomic_fetch_add(cnt, 1u, __ATOMIC_RELAXED, __HIP_MEMORY_SCOPE_AGENT);
            // prefetch next step's xw while the leader polls
            {
                const uint4* xp = (const uint4*)(sen_xbase(xw, xw_head, grow_e, t + 1)
                                                 + (size_t)(u0 + us) * 4);
                xq0 = xp[0]; xq1 = xp[1];
            }
            if (tid == 0) {
                unsigned target = 16u * (unsigned)(t + 1);
                while (__hip_atomic_load(cnt, __ATOMIC_RELAXED, __HIP_MEMORY_SCOPE_AGENT) < target)
                    __builtin_amdgcn_s_sleep(1);
            }
            __syncthreads();
        }
    }
}

// ============================================================================
// lstm_doc: persistent BiLSTM over 64 docs x 10 steps. Grid (16, 2).
// ============================================================================
__global__ __launch_bounds__(256, 2) void lstm_doc(
    const unsigned short* __restrict__ xw,
    const float* __restrict__ whh_f, const float* __restrict__ whh_b,
    unsigned short* hbA, unsigned short* hbB,
    float* __restrict__ documents,
    unsigned* bars)
{
    const int tid  = threadIdx.x;
    const int lane = tid & 63;
    const int w    = tid >> 6;
    const int n    = lane & 15;
    const int quad = lane >> 4;
    const int ug   = blockIdx.x;       // 0..15
    const int rg   = blockIdx.y;       // 0..1
    const int r0   = rg * 64;
    const int u0   = ug * 16;
    const bool bwd = (rg == 1);
    const float* whh = bwd ? whh_b : whh_f;
    unsigned* cnt = bars + rg * 16;

    __shared__ float G[64][68];

    bf16x8 Bf[4][8];
#pragma unroll
    for (int ct = 0; ct < 4; ct++) {
        const int c    = ct * 16 + n;
        const int grow = (c & 3) * 256 + u0 + (c >> 2);
        const float* wr = whh + (size_t)grow * 256;
#pragma unroll
        for (int ks = 0; ks < 8; ks++) {
            union { bf16x8 v; short s[8]; } tmp;
            const float* p = wr + ks * 32 + quad * 8;
#pragma unroll
            for (int j = 0; j < 8; j++) tmp.s[j] = (short)f2bf(p[j]);
            Bf[ct][ks] = tmp.v;
        }
    }

    float cr[4] = {0.f, 0.f, 0.f, 0.f};
    const int rr = tid >> 2;
    const int us = (tid & 3) * 4;
    const int grow_e = r0 + rr;
    const int seq = rr;

    uint4 xq0, xq1;
    {
        const unsigned short* xb = !bwd ? xw + ((size_t)seq * 10 + 0) * 2048
                                        : xw + ((size_t)seq * 10 + 9) * 2048 + 1024;
        const uint4* xp = (const uint4*)(xb + (size_t)(u0 + us) * 4);
        xq0 = xp[0]; xq1 = xp[1];
    }

    for (int t = 0; t < 10; t++) {
        const unsigned short* hp = (t & 1) ? hbB : hbA;
        unsigned short*       hq = (t & 1) ? hbA : hbB;
        const int dpos = !bwd ? t : 9 - t;
        const int doff = !bwd ? 0 : 256;

        {
            const unsigned long long* hrow =
                (const unsigned long long*)(hp + (size_t)(r0 + w * 16 + n) * 256);
            unsigned long long a0[8], a1[8];
#pragma unroll
            for (int ks = 0; ks < 8; ks++) {
                a0[ks] = __hip_atomic_load(hrow + ks * 8 + quad * 2,
                                           __ATOMIC_RELAXED, __HIP_MEMORY_SCOPE_AGENT);
                a1[ks] = __hip_atomic_load(hrow + ks * 8 + quad * 2 + 1,
                                           __ATOMIC_RELAXED, __HIP_MEMORY_SCOPE_AGENT);
            }
            f32x4 acc[4];
#pragma unroll
            for (int ct = 0; ct < 4; ct++) acc[ct] = (f32x4){0.f, 0.f, 0.f, 0.f};
#pragma unroll
            for (int ks = 0; ks < 8; ks++) {
                union { bf16x8 v; unsigned long long q[2]; } af;
                af.q[0] = a0[ks]; af.q[1] = a1[ks];
#pragma unroll
                for (int ct = 0; ct < 4; ct++)
                    acc[ct] = __builtin_amdgcn_mfma_f32_16x16x32_bf16(
                        af.v, Bf[ct][ks], acc[ct], 0, 0, 0);
            }
#pragma unroll
            for (int ct = 0; ct < 4; ct++)
#pragma unroll
                for (int r = 0; r < 4; r++)
                    G[w * 16 + quad * 4 + r][ct * 16 + n] = acc[ct][r];
        }
        __syncthreads();
        {
            const unsigned xwv[8] = {xq0.x, xq0.y, xq0.z, xq0.w,
                                     xq1.x, xq1.y, xq1.z, xq1.w};
            const float4* Gp = (const float4*)&G[rr][us * 4];
            unsigned long long hpack = 0ull;
            float hout[4];
#pragma unroll
            for (int p = 0; p < 4; p++) {
                float4 gv = Gp[p];
                unsigned wif = xwv[2 * p], wgo = xwv[2 * p + 1];
                float gi = gv.x + bflo(wif);
                float gf = gv.y + bfhi(wif);
                float gg = gv.z + bflo(wgo);
                float go = gv.w + bfhi(wgo);
                float cn = sigm(gf) * cr[p] + sigm(gi) * tanhf(gg);
                float hn = sigm(go) * tanhf(cn);
                cr[p] = cn; hout[p] = hn;
                hpack |= ((unsigned long long)f2bf(hn)) << (16 * p);
            }
            __hip_atomic_store((unsigned long long*)(hq + (size_t)grow_e * 256 + u0 + us),
                               hpack, __ATOMIC_RELAXED, __HIP_MEMORY_SCOPE_AGENT);
            *(float4*)(documents + (size_t)(seq * 10 + dpos) * 512 + doff + u0 + us) =
                *(float4*)hout;
        }
        if (t < 9) {
            __syncthreads();
            if (tid == 0)
                __hip_atomic_fetch_add(cnt, 1u, __ATOMIC_RELAXED, __HIP_MEMORY_SCOPE_AGENT);
            {
                const unsigned short* xb = !bwd ? xw + ((size_t)seq * 10 + t + 1) * 2048
                                                : xw + ((size_t)seq * 10 + 8 - t) * 2048 + 1024;
                const uint4* xp = (const uint4*)(xb + (size_t)(u0 + us) * 4);
                xq0 = xp[0]; xq1 = xp[1];
            }
            if (tid == 0) {
                unsigned target = 16u * (unsigned)(t + 1);
                while (__hip_atomic_load(cnt, __ATOMIC_RELAXED, __HIP_MEMORY_SCOPE_AGENT) < target)
                    __builtin_amdgcn_s_sleep(1);
            }
            __syncthreads();
        }
    }
}

// ============================================================================
// source_bias (url-grouped): one block per url; reads the url's 1 MB expert
// matrix ONCE for all its tokens (padded chunks of 16, unrolled registers).
// ============================================================================
__global__ __launch_bounds__(256) void source_bias(
    const float* __restrict__ sentences, const int* __restrict__ urls,
    const float* __restrict__ trans, const float* __restrict__ sb_bias,
    unsigned* __restrict__ biasedBf)
{
    const int u = blockIdx.x;
    const int tid = threadIdx.x;
    __shared__ int toks[656];
    __shared__ int ntok;
    __shared__ float sv[16][512];
    if (tid == 0) ntok = 0;
    __syncthreads();
    for (int i = tid; i < 640; i += 256)
        if (urls[i] == u) { int p = atomicAdd(&ntok, 1); toks[p] = i; }
    __syncthreads();
    const int nt = ntok;
    if (nt == 0) return;
    const int ntp = (nt + 15) & ~15;
    // pad with first token (duplicate writes of identical values are benign)
    for (int i = nt + tid; i < ntp; i += 256) toks[i] = toks[0];
    __syncthreads();

    const int e = tid;                       // column pair (2e, 2e+1)
    const float2 bv = ((const float2*)(sb_bias + (size_t)u * 512))[e];
    const float2* Tm = (const float2*)(trans + (size_t)u * 512 * 512);

    for (int c0 = 0; c0 < ntp; c0 += 16) {
        for (int i = tid; i < 16 * 512; i += 256) {
            int tk = i >> 9, d = i & 511;
            sv[tk][d] = sentences[(size_t)toks[c0 + tk] * 512 + d];
        }
        __syncthreads();
        float ax[16], ay[16];
#pragma unroll
        for (int tk = 0; tk < 16; tk++) { ax[tk] = 0.f; ay[tk] = 0.f; }
        for (int d = 0; d < 512; d++) {
            float2 tv = Tm[(size_t)d * 256 + e];
#pragma unroll
            for (int tk = 0; tk < 16; tk++) {
                float s = sv[tk][d];
                ax[tk] += s * tv.x;
                ay[tk] += s * tv.y;
            }
        }
#pragma unroll
        for (int tk = 0; tk < 16; tk++) {
            int tkn = toks[c0 + tk];
            float x = tanhf(ax[tk] + bv.x), y = tanhf(ay[tk] + bv.y);
            biasedBf[(size_t)tkn * 256 + e] = (unsigned)f2bf(x) | ((unsigned)f2bf(y) << 16);
        }
        __syncthreads();
    }
}

// ============================================================================
// attn_heads: v = attn_W @ heading, scores -> softmax -> doc_rep -> MLP heads.
// ============================================================================
__global__ __launch_bounds__(256) void attn_heads(
    const float* __restrict__ documents, const float* __restrict__ headings,
    const float* __restrict__ attn_W, const float* __restrict__ attn_b,
    const float* __restrict__ bW1, const float* __restrict__ bb1,
    const float* __restrict__ bW2, const float* __restrict__ bb2,
    const float* __restrict__ tW1, const float* __restrict__ tb1,
    const float* __restrict__ tW2, const float* __restrict__ tb2,
    float* __restrict__ out)
{
    const int b = blockIdx.x, tid = threadIdx.x;
    const int lane = tid & 63, wv_ = tid >> 6;
    __shared__ float hh[512], vv[512], dr[512], h1s[256], t1s[256], sw[12], lg[5];
    for (int i = tid; i < 512; i += 256) hh[i] = headings[(size_t)b * 512 + i];
    __syncthreads();
    for (int d = tid; d < 512; d += 256) {
        float a = 0.f;
        const float* wr = attn_W + (size_t)d * 512;
        for (int e = 0; e < 512; e++) a += wr[e] * hh[e];
        vv[d] = a;
    }
    __syncthreads();
    for (int q = 0; q < 3; q++) {
        int s = q * 4 + wv_;
        float p = 0.f;
        if (s < 10) {
            const float* dp = documents + (size_t)(b * 10 + s) * 512;
            for (int d = lane; d < 512; d += 64) p += dp[d] * vv[d];
        }
#pragma unroll
        for (int off = 32; off > 0; off >>= 1) p += __shfl_down(p, off, 64);
        if (s < 10 && lane == 0) sw[s] = p + attn_b[0];
    }
    __syncthreads();
    if (tid == 0) {
        float mx = sw[0];
        for (int s = 1; s < 10; s++) mx = fmaxf(mx, sw[s]);
        float sum = 0.f;
        for (int s = 0; s < 10; s++) { sw[s] = expf(sw[s] - mx); sum += sw[s]; }
        for (int s = 0; s < 10; s++) sw[s] /= sum;
    }
    __syncthreads();
    for (int d = tid; d < 512; d += 256) {
        float a = 0.f;
#pragma unroll
        for (int s = 0; s < 10; s++) a += sw[s] * documents[(size_t)(b * 10 + s) * 512 + d];
        dr[d] = a;
    }
    __syncthreads();
    {
        float a = bb1[tid], a2 = tb1[tid];
        const float* w1 = bW1 + (size_t)tid * 512;
        const float* w2 = tW1 + (size_t)tid * 512;
        for (int k = 0; k < 512; k++) { float x = dr[k]; a += x * w1[k]; a2 += x * w2[k]; }
        h1s[tid] = tanhf(a); t1s[tid] = tanhf(a2);
    }
    __syncthreads();
    if (tid < 5) {
        float a = bb2[tid];
        const float* wp = bW2 + (size_t)tid * 256;
        for (int k = 0; k < 256; k++) a += h1s[k] * wp[k];
        lg[tid] = tanhf(a);
    }
    if (tid == 32) {
        float a = tb2[0];
        for (int k = 0; k < 256; k++) a += t1s[k] * tW2[k];
        out[320 + b] = 1.f / (1.f + expf(-tanhf(a)));
    }
    __syncthreads();
    if (tid == 0) {
        float mx = lg[0];
        for (int j = 1; j < 5; j++) mx = fmaxf(mx, lg[j]);
        float sum = 0.f, e[5];
        for (int j = 0; j < 5; j++) { e[j] = expf(lg[j] - mx); sum += e[j]; }
        for (int j = 0; j < 5; j++) out[b * 5 + j] = e[j] / sum;
    }
}

extern "C" void kernel_launch(void* const* d_in, const int* in_sizes, int n_in,
                              void* d_out, int out_size, void* d_ws, size_t ws_size,
                              hipStream_t stream)
{
    (void)in_sizes; (void)n_in; (void)out_size; (void)ws_size;
    const int*   input_ids = (const int*)d_in[0];
    const int*   urls      = (const int*)d_in[1];
    const int*   titles    = (const int*)d_in[2];
    const float* emb       = (const float*)d_in[3];
    const float* sen_wih_f = (const float*)d_in[4];
    const float* sen_whh_f = (const float*)d_in[5];
    const float* sen_b_f   = (const float*)d_in[6];
    const float* sen_wih_b = (const float*)d_in[7];
    const float* sen_whh_b = (const float*)d_in[8];
    const float* sen_b_b   = (const float*)d_in[9];
    const float* trans     = (const float*)d_in[10];
    const float* sb_bias   = (const float*)d_in[11];
    const float* doc_wih_f = (const float*)d_in[12];
    const float* doc_whh_f = (const float*)d_in[13];
    const float* doc_b_f   = (const float*)d_in[14];
    const float* doc_wih_b = (const float*)d_in[15];
    const float* doc_whh_b = (const float*)d_in[16];
    const float* doc_b_b   = (const float*)d_in[17];
    const float* attn_W    = (const float*)d_in[18];
    const float* attn_b    = (const float*)d_in[19];
    const float* bias_W1   = (const float*)d_in[20];
    const float* bias_b1   = (const float*)d_in[21];
    const float* bias_W2   = (const float*)d_in[22];
    const float* bias_b2   = (const float*)d_in[23];
    const float* truth_W1  = (const float*)d_in[24];
    const float* truth_b1  = (const float*)d_in[25];
    const float* truth_W2  = (const float*)d_in[26];
    const float* truth_b2  = (const float*)d_in[27];
    float* out = (float*)d_out;

    // ------------------------------------------------------------------
    // Workspace (offsets in FLOATS), total 25.6M floats = 102 MB.
    // xw_all (bf16) @0 .. 20,643,840. Dead after lstm_sen; overlaid by:
    //   biasedBf @0 (163,840) | xw_doc(bf16) @163,840 (655,360)
    //   | documents @819,200 (327,680).
    // Persistent zone @20,643,840: sentences(327,680), headings(32,768),
    //   hbA/hbB/hdA/hdB/bars — one contiguous memset for the state block.
    // Abf @21,500,000 (3,225,600) | Wsen @24,725,600 | Wdoc @25,053,280.
    // ------------------------------------------------------------------
    float* ws = (float*)d_ws;
    unsigned short* xw_all  = (unsigned short*)ws;
    unsigned short* xw_head = xw_all + (size_t)19200 * 2048;
    unsigned* biasedBf      = (unsigned*)(ws + 0);
    unsigned short* xw_doc  = (unsigned short*)(ws + 163840);
    float* documents        = ws + 819200;

    float* sentences   = ws + 20643840;
    float* headings    = ws + 20971520;
    unsigned short* hbA = (unsigned short*)(ws + 21004288);
    unsigned short* hbB = (unsigned short*)(ws + 21184512);
    unsigned short* hdA = (unsigned short*)(ws + 21364736);
    unsigned short* hdB = (unsigned short*)(ws + 21381120);
    unsigned* barsS    = (unsigned*)(ws + 21397504);   // 22 counters, 16-uint stride
    unsigned* barsD    = barsS + 22 * 16;              // 2 counters

    unsigned* Abf      = (unsigned*)(ws + 21500000);
    unsigned* Wsen     = (unsigned*)(ws + 24725600);
    unsigned* Wdoc     = (unsigned*)(ws + 25053280);

    dim3 blk(256);

    // single memset covers hbA..hbB..hdA..hdB..bars (contiguous)
    hipMemsetAsync(hbA, 0, ((size_t)21397504 + 24 * 16 - 21004288) * sizeof(float), stream);

    // D1: gather + bf16 casts
    prep_cast<<<dim3((N0 + N1 + N2 + 255) / 256), blk, 0, stream>>>(
        input_ids, titles, emb, sen_wih_f, sen_wih_b, doc_wih_f, doc_wih_b,
        Abf, Wsen, Wdoc);

    // D2: sentence+title input projection -> bf16 xw
    proj_mfma<<<dim3(158, 16), blk, 0, stream>>>(
        (const unsigned short*)Abf, 20160, 320,
        (const unsigned short*)Wsen, sen_b_f, sen_b_b, xw_all);

    // D3: persistent sentence/heading BiLSTM
    lstm_sen<<<dim3(16, 22), blk, 0, stream>>>(
        xw_all, xw_head, sen_whh_f, sen_whh_b, hbA, hbB,
        sentences, headings, barsS);

    // D4: SourceBias (url-grouped)
    source_bias<<<dim3(64), blk, 0, stream>>>(sentences, urls, trans, sb_bias, biasedBf);

    // D5: document input projection -> bf16 xw_doc
    proj_mfma<<<dim3(5, 16), blk, 0, stream>>>(
        (const unsigned short*)biasedBf, 640, 512,
        (const unsigned short*)Wdoc, doc_b_f, doc_b_b, xw_doc);

    // D6: persistent document BiLSTM
    lstm_doc<<<dim3(16, 2), blk, 0, stream>>>(
        xw_doc, doc_whh_f, doc_whh_b, hdA, hdB, documents, barsD);

    // D7: attention + heads (attn_v fused in)
    attn_heads<<<dim3(64), blk, 0, stream>>>(documents, headings, attn_W, attn_b,
                                             bias_W1, bias_b1, bias_W2, bias_b2,
                                             truth_W1, truth_b1, truth_W2, truth_b2,
                                             out);
}